// Round 4
// baseline (55.073 us; speedup 1.0000x reference)
//
#include <hip/hip_runtime.h>

#define VOCAB 100000
#define EMBED 128
#define BATCH 16384
#define WIN 10
#define NEG 10

// 32 lanes per batch element, 2 elements per wave64, 8 per 256-thread block.
// Lane owns one float4 (16B); row gather = 32 lanes x 16B = 512B contiguous.
// Grid = 2048 blocks -> 8192 waves = every wave slot on the device (max TLP
// for latency hiding on the random row gathers).
// Indices are fetched lane-parallel (3 masked vmem ops) then shfl-broadcast.
__global__ __launch_bounds__(256, 4) void cbow_loss_kernel(
    const float* __restrict__ target_table,   // [VOCAB][EMBED]
    const float* __restrict__ context_table,  // [VOCAB][EMBED]
    const int*   __restrict__ context,        // [B]
    const int*   __restrict__ target,         // [B][WIN]
    const int*   __restrict__ negatives,      // [B][NEG]
    float*       __restrict__ out)            // [1], pre-zeroed
{
    const int tid  = threadIdx.x;
    const int lane = tid & 31;   // within 32-lane group
    const int grp  = tid >> 5;   // 0..7
    const int b    = blockIdx.x * 8 + grp;

    const float4* tt4 = reinterpret_cast<const float4*>(target_table);
    const float4* ct4 = reinterpret_cast<const float4*>(context_table);
    // row = EMBED/4 = 32 float4s; lane owns float4 #lane.

    // ---- lane-parallel index fetch: lanes 0..9 -> target window,
    //      lane 10 -> context, lanes 11..20 -> negatives ----
    int myidx = 0;
    if (lane < WIN)                 myidx = target[b * WIN + lane];
    else if (lane == WIN)           myidx = context[b];
    else if (lane < 2 * WIN + 1)    myidx = negatives[b * NEG + (lane - WIN - 1)];

    int tidx[WIN], nidx[NEG];
    #pragma unroll
    for (int w = 0; w < WIN; ++w) tidx[w] = __shfl(myidx, w, 32);
    const int cidx = __shfl(myidx, WIN, 32);
    #pragma unroll
    for (int k = 0; k < NEG; ++k) nidx[k] = __shfl(myidx, WIN + 1 + k, 32);

    // ---- trg = mean over window ----
    float4 t = make_float4(0.f, 0.f, 0.f, 0.f);
    #pragma unroll
    for (int w = 0; w < WIN; ++w) {
        const float4 v = tt4[(long long)tidx[w] * (EMBED / 4) + lane];
        t.x += v.x; t.y += v.y; t.z += v.z; t.w += v.w;
    }
    const float s = 1.0f / WIN;
    t.x *= s; t.y *= s; t.z *= s; t.w *= s;

    // ---- 11 dot-product partials ----
    float sc[1 + NEG];
    {
        const float4 v = ct4[(long long)cidx * (EMBED / 4) + lane];
        sc[0] = fmaf(t.x, v.x, fmaf(t.y, v.y, fmaf(t.z, v.z, t.w * v.w)));
    }
    #pragma unroll
    for (int k = 0; k < NEG; ++k) {
        const float4 v = ct4[(long long)nidx[k] * (EMBED / 4) + lane];
        sc[1 + k] = fmaf(t.x, v.x, fmaf(t.y, v.y, fmaf(t.z, v.z, t.w * v.w)));
    }

    // ---- butterfly reduce within 32-lane group (5 steps, 11 values) ----
    #pragma unroll
    for (int off = 16; off >= 1; off >>= 1) {
        #pragma unroll
        for (int i = 0; i < 1 + NEG; ++i) sc[i] += __shfl_xor(sc[i], off, 32);
    }

    // ---- per-block accumulation ----
    __shared__ float bsum;
    if (tid == 0) bsum = 0.f;
    __syncthreads();

    if (lane == 0) {
        float x = fminf(fmaxf(sc[0], -10.f), 10.f);
        float loss = log1pf(expf(-x));
        #pragma unroll
        for (int k = 0; k < NEG; ++k) {
            float y = fminf(fmaxf(sc[1 + k], -10.f), 10.f);
            loss += log1pf(expf(y));
        }
        atomicAdd(&bsum, loss);
    }
    __syncthreads();

    if (tid == 0) {
        atomicAdd(out, bsum * (1.0f / BATCH));
    }
}

extern "C" void kernel_launch(void* const* d_in, const int* in_sizes, int n_in,
                              void* d_out, int out_size, void* d_ws, size_t ws_size,
                              hipStream_t stream) {
    const float* target_table  = (const float*)d_in[0];
    const float* context_table = (const float*)d_in[1];
    const int*   context       = (const int*)d_in[2];
    const int*   target        = (const int*)d_in[3];
    const int*   negatives     = (const int*)d_in[4];
    float* out = (float*)d_out;

    hipMemsetAsync(out, 0, sizeof(float), stream);

    cbow_loss_kernel<<<BATCH / 8, 256, 0, stream>>>(
        target_table, context_table, context, target, negatives, out);
}

// Round 5
// 53.308 us; speedup vs baseline: 1.0331x; 1.0331x over previous
//
#include <hip/hip_runtime.h>

#define VOCAB 100000
#define EMBED 128
#define BATCH 16384
#define WIN 10
#define NEG 10

typedef float f32x4 __attribute__((ext_vector_type(4)));

// Raw global load the compiler cannot re-serialize: issues immediately,
// completion tracked only by vmcnt. MUST be followed by an explicit
// s_waitcnt before the result is consumed.
__device__ __forceinline__ f32x4 gload(const f32x4* p) {
    f32x4 r;
    asm volatile("global_load_dwordx4 %0, %1, off" : "=v"(r) : "v"(p) : "memory");
    return r;
}

// 32 lanes per batch element (lane owns one float4 = 16B; a row gather is
// 32 lanes x 16B = 512B contiguous). All 21 row loads per element are issued
// back-to-back via inline asm -> 21 outstanding loads per wave-group, then
// consumed with counted waits (window rows at vmcnt(11), score rows at 0).
__global__ __launch_bounds__(256, 3) void cbow_loss_kernel(
    const float* __restrict__ target_table,   // [VOCAB][EMBED]
    const float* __restrict__ context_table,  // [VOCAB][EMBED]
    const int*   __restrict__ context,        // [B]
    const int*   __restrict__ target,         // [B][WIN]
    const int*   __restrict__ negatives,      // [B][NEG]
    float*       __restrict__ out)            // [1], pre-zeroed
{
    const int tid  = threadIdx.x;
    const int lane = tid & 31;   // within 32-lane group
    const int grp  = tid >> 5;   // 0..7
    const int b    = blockIdx.x * 8 + grp;

    const f32x4* tt4 = reinterpret_cast<const f32x4*>(target_table);
    const f32x4* ct4 = reinterpret_cast<const f32x4*>(context_table);

    // ---- lane-parallel index fetch (consumed via shfl BEFORE the asm
    //      region, so vmcnt is drained of compiler loads by then) ----
    int myidx = 0;
    if (lane < WIN)                 myidx = target[b * WIN + lane];
    else if (lane == WIN)           myidx = context[b];
    else if (lane < 2 * WIN + 1)    myidx = negatives[b * NEG + (lane - WIN - 1)];

    int idxs[2 * WIN + 1];
    #pragma unroll
    for (int i = 0; i < 2 * WIN + 1; ++i) idxs[i] = __shfl(myidx, i, 32);

    // ---- issue ALL 21 row gathers (ordered asm, 21 outstanding) ----
    f32x4 w[WIN];
    #pragma unroll
    for (int i = 0; i < WIN; ++i)
        w[i] = gload(tt4 + (long long)idxs[i] * (EMBED / 4) + lane);

    f32x4 c[1 + NEG];
    #pragma unroll
    for (int k = 0; k < 1 + NEG; ++k)
        c[k] = gload(ct4 + (long long)idxs[WIN + k] * (EMBED / 4) + lane);

    // ---- window rows done (10 oldest of 21): sum + mean while the 11
    //      score rows are still in flight ----
    asm volatile("s_waitcnt vmcnt(11)" ::: "memory");
    __builtin_amdgcn_sched_barrier(0);

    #pragma unroll
    for (int stride = 1; stride < WIN; stride <<= 1) {
        #pragma unroll
        for (int i = 0; i + stride < WIN; i += 2 * stride) {
            w[i].x += w[i + stride].x; w[i].y += w[i + stride].y;
            w[i].z += w[i + stride].z; w[i].w += w[i + stride].w;
        }
    }
    const float s = 1.0f / WIN;
    f32x4 t = w[0];
    t.x *= s; t.y *= s; t.z *= s; t.w *= s;

    // ---- score rows done: 11 dot-product partials ----
    asm volatile("s_waitcnt vmcnt(0)" ::: "memory");
    __builtin_amdgcn_sched_barrier(0);

    float sc[1 + NEG];
    #pragma unroll
    for (int i = 0; i < 1 + NEG; ++i)
        sc[i] = fmaf(t.x, c[i].x, fmaf(t.y, c[i].y, fmaf(t.z, c[i].z, t.w * c[i].w)));

    // ---- butterfly reduce within 32-lane group (5 steps, 11 values) ----
    #pragma unroll
    for (int off = 16; off >= 1; off >>= 1) {
        #pragma unroll
        for (int i = 0; i < 1 + NEG; ++i) sc[i] += __shfl_xor(sc[i], off, 32);
    }

    // ---- per-block accumulation ----
    __shared__ float bsum;
    if (tid == 0) bsum = 0.f;
    __syncthreads();

    if (lane == 0) {
        float x = fminf(fmaxf(sc[0], -10.f), 10.f);
        float loss = log1pf(expf(-x));
        #pragma unroll
        for (int k = 0; k < NEG; ++k) {
            float y = fminf(fmaxf(sc[1 + k], -10.f), 10.f);
            loss += log1pf(expf(y));
        }
        atomicAdd(&bsum, loss);
    }
    __syncthreads();

    if (tid == 0) {
        atomicAdd(out, bsum * (1.0f / BATCH));
    }
}

extern "C" void kernel_launch(void* const* d_in, const int* in_sizes, int n_in,
                              void* d_out, int out_size, void* d_ws, size_t ws_size,
                              hipStream_t stream) {
    const float* target_table  = (const float*)d_in[0];
    const float* context_table = (const float*)d_in[1];
    const int*   context       = (const int*)d_in[2];
    const int*   target        = (const int*)d_in[3];
    const int*   negatives     = (const int*)d_in[4];
    float* out = (float*)d_out;

    hipMemsetAsync(out, 0, sizeof(float), stream);

    cbow_loss_kernel<<<BATCH / 8, 256, 0, stream>>>(
        target_table, context_table, context, target, negatives, out);
}

// Round 6
// 44.057 us; speedup vs baseline: 1.2501x; 1.2100x over previous
//
#include <hip/hip_runtime.h>

#define VOCAB 100000
#define EMBED 128
#define BATCH 16384
#define WIN 10
#define NEG 10
#define EPB 16          // elements (batch items) per 256-thread block
#define NIDX (2 * WIN + 1)  // 21 indices per element

// R2-proven shape: 16 lanes per batch element, 4 elements per wave64, 16 per
// block. Lane owns 8 consecutive floats (2x float4 = 32B); one row gather =
// 16 lanes x 32B = 512B contiguous, and each load instruction services 4
// rows (one per group). New vs R2: all 21*16 = 336 indices for the block are
// staged in LDS by 3 coalesced cooperative loads, removing 21 broadcast
// index-load vmem instructions (and their latency) from the front of every
// gather dependency chain.
__global__ __launch_bounds__(256) void cbow_loss_kernel(
    const float* __restrict__ target_table,   // [VOCAB][EMBED]
    const float* __restrict__ context_table,  // [VOCAB][EMBED]
    const int*   __restrict__ context,        // [B]
    const int*   __restrict__ target,         // [B][WIN]
    const int*   __restrict__ negatives,      // [B][NEG]
    float*       __restrict__ out)            // [1], pre-zeroed
{
    const int tid    = threadIdx.x;
    const int lane16 = tid & 15;
    const int grp    = tid >> 4;           // 0..15 = element within block
    const int b0     = blockIdx.x * EPB;   // first element of block
    const int b      = b0 + grp;

    // ---- cooperative index staging: slots [0..9]=window, [10]=context,
    //      [11..20]=negatives ----
    __shared__ int s_idx[EPB][NIDX];
    for (int i = tid; i < EPB * NIDX; i += 256) {
        const int e = i / NIDX;
        const int s = i - e * NIDX;
        int v;
        if (s < WIN)            v = target[(b0 + e) * WIN + s];
        else if (s == WIN)      v = context[b0 + e];
        else                    v = negatives[(b0 + e) * NEG + (s - WIN - 1)];
        s_idx[e][s] = v;
    }
    __syncthreads();

    const float4* tt4 = reinterpret_cast<const float4*>(target_table);
    const float4* ct4 = reinterpret_cast<const float4*>(context_table);
    const int lo = lane16 * 2;  // row = 32 float4s; lane owns [lo, lo+1]

    // ---- trg = mean over window (accumulate-as-you-go; compiler pipelines) ----
    float4 t0 = make_float4(0.f, 0.f, 0.f, 0.f);
    float4 t1 = make_float4(0.f, 0.f, 0.f, 0.f);
    #pragma unroll
    for (int w = 0; w < WIN; ++w) {
        const float4* r = tt4 + (long long)s_idx[grp][w] * (EMBED / 4) + lo;
        const float4 a = r[0];
        const float4 c = r[1];
        t0.x += a.x; t0.y += a.y; t0.z += a.z; t0.w += a.w;
        t1.x += c.x; t1.y += c.y; t1.z += c.z; t1.w += c.w;
    }
    const float s = 1.0f / WIN;
    t0.x *= s; t0.y *= s; t0.z *= s; t0.w *= s;
    t1.x *= s; t1.y *= s; t1.z *= s; t1.w *= s;

    // ---- 11 dot-product partials (slot 10 = context, 11.. = negatives) ----
    float sc[1 + NEG];
    #pragma unroll
    for (int k = 0; k < 1 + NEG; ++k) {
        const float4* r = ct4 + (long long)s_idx[grp][WIN + k] * (EMBED / 4) + lo;
        const float4 a = r[0];
        const float4 c = r[1];
        sc[k] = fmaf(t0.x, a.x, fmaf(t0.y, a.y, fmaf(t0.z, a.z, fmaf(t0.w, a.w,
                fmaf(t1.x, c.x, fmaf(t1.y, c.y, fmaf(t1.z, c.z, t1.w * c.w)))))));
    }

    // ---- butterfly reduce within 16-lane group (4 steps, 11 values) ----
    #pragma unroll
    for (int off = 8; off >= 1; off >>= 1) {
        #pragma unroll
        for (int i = 0; i < 1 + NEG; ++i) sc[i] += __shfl_xor(sc[i], off, 16);
    }

    // ---- per-block accumulation ----
    __shared__ float bsum;
    if (tid == 0) bsum = 0.f;
    __syncthreads();

    if (lane16 == 0) {
        float x = fminf(fmaxf(sc[0], -10.f), 10.f);
        float loss = log1pf(expf(-x));
        #pragma unroll
        for (int k = 0; k < NEG; ++k) {
            float y = fminf(fmaxf(sc[1 + k], -10.f), 10.f);
            loss += log1pf(expf(y));
        }
        atomicAdd(&bsum, loss);
    }
    __syncthreads();

    if (tid == 0) {
        atomicAdd(out, bsum * (1.0f / BATCH));
    }
}

extern "C" void kernel_launch(void* const* d_in, const int* in_sizes, int n_in,
                              void* d_out, int out_size, void* d_ws, size_t ws_size,
                              hipStream_t stream) {
    const float* target_table  = (const float*)d_in[0];
    const float* context_table = (const float*)d_in[1];
    const int*   context       = (const int*)d_in[2];
    const int*   target        = (const int*)d_in[3];
    const int*   negatives     = (const int*)d_in[4];
    float* out = (float*)d_out;

    hipMemsetAsync(out, 0, sizeof(float), stream);

    cbow_loss_kernel<<<BATCH / EPB, 256, 0, stream>>>(
        target_table, context_table, context, target, negatives, out);
}